// Round 3
// baseline (164.352 us; speedup 1.0000x reference)
//
#include <hip/hip_runtime.h>
#include <hip/hip_bf16.h>
#include <stdint.h>

// LocalSlidingWindowAttention: B=2, T=2048, D=1024, H=16, hd=64, keys j in [i, i+64].
// f32 in/out. Build:
//   convert_all (r7) -> gemm1_qkv_8ph (256x256 tile, BK=64, 8-wave phase-split
//   schedule w/ counted-vmcnt prefetch + XOR LDS swizzle + setprio; m201 template)
//   -> attn_mfma (r3, proven) -> gemm2_out (r8, proven).
// Session model: total ~= kernels + ~85us fixed harness overhead.
// Prev gemm1 (128x128 m97-structure) measured 43.7us; predicted ~25us here.
// NOTE r2: rounds 0-2 all GPUAcquisitionTimeout; kernel re-audited statically
// (staging/read bijection, bank minimality, dbuf race proof) and resubmitted.

typedef short bf16x8 __attribute__((ext_vector_type(8)));
typedef float f32x4 __attribute__((ext_vector_type(4)));

typedef const __attribute__((address_space(1))) void* gptr_t;
typedef __attribute__((address_space(3))) void* lptr_t;

#define BAR()        asm volatile("s_barrier" ::: "memory")
#define WAIT_LGKM0() asm volatile("s_waitcnt lgkmcnt(0)" ::: "memory")
#define WAIT_VM0()   asm volatile("s_waitcnt vmcnt(0)" ::: "memory")

__device__ __forceinline__ float bf2f(short u) {
    union { float f; uint32_t i; } x;
    x.i = ((uint32_t)(uint16_t)u) << 16;
    return x.f;
}
__device__ __forceinline__ short f2bf(float f) {
    __hip_bfloat16 h = __float2bfloat16(f);  // RNE
    return *reinterpret_cast<short*>(&h);
}

// Convert x, w_qkv, w_out to bf16. 8 elems/thread.
__global__ __launch_bounds__(256)
void convert_all(const float* __restrict__ x, const float* __restrict__ wq,
                 const float* __restrict__ wo,
                 short* __restrict__ xb, short* __restrict__ wqb, short* __restrict__ wob) {
    int i = blockIdx.x * 256 + threadIdx.x;
    const float* src; short* dst; int o;
    if      (i <  524288) { src = x;  dst = xb;  o = i; }
    else if (i <  917504) { src = wq; dst = wqb; o = i - 524288; }
    else                  { src = wo; dst = wob; o = i - 917504; }
    const int e = o * 8;
    float4 a = *(const float4*)(src + e);
    float4 b = *(const float4*)(src + e + 4);
    short t[8];
    t[0] = f2bf(a.x); t[1] = f2bf(a.y); t[2] = f2bf(a.z); t[3] = f2bf(a.w);
    t[4] = f2bf(b.x); t[5] = f2bf(b.y); t[6] = f2bf(b.z); t[7] = f2bf(b.w);
    *(uint4*)(dst + e) = *(const uint4*)t;
}

// GEMM1, 8-phase 256x256 schedule. C[m,n] = sum_k A[m,k]*Bt[n,k] + bias[n], bf16 out.
// 512 threads = 8 waves (2M x 4N), per-wave output 128x64. BK=64, double-buffered
// LDS (128 KiB). Per K-tile: 4 phases; phase p computes C-quadrant (mh,nh)=(p>>1,p&1)
// = 64x32 (16 MFMA), interleaved with ds_reads of that quadrant's fragments and (at
// phase 0) the 8 global_load_lds prefetching kt+1 into the other buffer. One counted
// drain per K-tile: vmcnt(0)+barrier at phase 3 end (~3 phases of latency cover).
// LDS swizzle (T2): 16B-slot ^= (row&7) applied on the GLOBAL source address at stage
// time (global_load_lds dest is linear, rule #21) and on the ds_read address. Spreads
// a wave's 64 b128 lanes over all 8 slot groups (theoretical bank minimum) vs 4
// groups linear -> ~2x faster LDS-read path.
// Race safety: stages for kt+1 target buf[(kt+1)&1], whose last ds_reads (for kt-1)
// completed before the kt-1 boundary barrier -> all stage issues are ordered after.
__global__ __launch_bounds__(512, 1)
void gemm1_qkv_8ph(const short* __restrict__ A, const short* __restrict__ Bt,
                   const float* __restrict__ bias, short* __restrict__ C,
                   int M, int N, int K) {
    __shared__ short As[2][256 * 64];   // 64 KiB
    __shared__ short Bs[2][256 * 64];   // 64 KiB

    const int tid  = threadIdx.x;
    const int lane = tid & 63;
    const int w    = tid >> 6;        // 0..7
    const int qd   = lane >> 4;       // 0..3
    const int l16  = lane & 15;
    const int wm   = w >> 2;          // 0..1  (128 rows each)
    const int wn   = w & 3;           // 0..3  (64 cols each)

    // XCD-chunked bijective swizzle (nwg=192, 192%8==0): XCD g gets 24 contiguous
    // wg = 2 m-panels x all 12 n-tiles -> A-panel L2 reuse.
    const int nTn   = N >> 8;                     // 12
    const int chunk = gridDim.x >> 3;             // 24
    const int wg    = (blockIdx.x & 7) * chunk + (blockIdx.x >> 3);
    const int mt    = wg / nTn;
    const int nt    = wg - mt * nTn;
    const int mBase = mt << 8;
    const int nBase = nt << 8;

    // Precompute per-thread staging sources (global, slot pre-XOR'd) for the 4
    // rounds covering each 256x64 tile (2048 granules of 16B; granule = rr*512+tid).
    const short* gAp[4];
    const short* gBp[4];
#pragma unroll
    for (int rr = 0; rr < 4; ++rr) {
        const int p    = rr * 512 + tid;
        const int row  = p >> 3;                  // 0..255
        const int slot = (p & 7) ^ (row & 7);     // inverse swizzle on source
        gAp[rr] = A  + (size_t)(mBase + row) * K + slot * 8;
        gBp[rr] = Bt + (size_t)(nBase + row) * K + slot * 8;
    }

    f32x4 acc[8][4] = {};
    const int nk = K >> 6;                        // 16

    // Prologue: stage K-tile 0 into buf 0.
#pragma unroll
    for (int rr = 0; rr < 4; ++rr) {
        lptr_t la = (lptr_t)(&As[0][0] + (rr * 512 + w * 64) * 8);
        lptr_t lb = (lptr_t)(&Bs[0][0] + (rr * 512 + w * 64) * 8);
        __builtin_amdgcn_global_load_lds((gptr_t)gAp[rr], la, 16, 0, 0);
        __builtin_amdgcn_global_load_lds((gptr_t)gBp[rr], lb, 16, 0, 0);
    }
    WAIT_VM0();
    BAR();

    for (int kt = 0; kt < nk; ++kt) {
        const int cur = kt & 1;
        const short* Ab = &As[cur][0];
        const short* Bb = &Bs[cur][0];

#pragma unroll
        for (int ph = 0; ph < 4; ++ph) {
            const int mh = ph >> 1, nh = ph & 1;

            // ds-load this quadrant's fragments (8 A + 4 B ds_read_b128, swizzled).
            bf16x8 af[4][2], bfr[2][2];
#pragma unroll
            for (int mi = 0; mi < 4; ++mi) {
                const int row = wm * 128 + mh * 64 + mi * 16 + l16;
#pragma unroll
                for (int kh = 0; kh < 2; ++kh) {
                    const int slot = (kh * 4 + qd) ^ (row & 7);
                    af[mi][kh] = *(const bf16x8*)(Ab + row * 64 + slot * 8);
                }
            }
#pragma unroll
            for (int ni = 0; ni < 2; ++ni) {
                const int row = wn * 64 + nh * 32 + ni * 16 + l16;
#pragma unroll
                for (int kh = 0; kh < 2; ++kh) {
                    const int slot = (kh * 4 + qd) ^ (row & 7);
                    bfr[ni][kh] = *(const bf16x8*)(Bb + row * 64 + slot * 8);
                }
            }

            // Phase 0: issue all 8 prefetch loads for kt+1 into the idle buffer.
            if (ph == 0 && kt + 1 < nk) {
                const int nb = cur ^ 1;
                const size_t kadv = (size_t)(kt + 1) * 64;
#pragma unroll
                for (int rr = 0; rr < 4; ++rr) {
                    lptr_t la = (lptr_t)(&As[nb][0] + (rr * 512 + w * 64) * 8);
                    lptr_t lb = (lptr_t)(&Bs[nb][0] + (rr * 512 + w * 64) * 8);
                    __builtin_amdgcn_global_load_lds((gptr_t)(gAp[rr] + kadv), la, 16, 0, 0);
                    __builtin_amdgcn_global_load_lds((gptr_t)(gBp[rr] + kadv), lb, 16, 0, 0);
                }
            }

            BAR();
            WAIT_LGKM0();
            __builtin_amdgcn_sched_barrier(0);

            __builtin_amdgcn_s_setprio(1);
#pragma unroll
            for (int mi = 0; mi < 4; ++mi)
#pragma unroll
                for (int ni = 0; ni < 2; ++ni) {
                    f32x4 c = acc[mh * 4 + mi][nh * 2 + ni];
                    c = __builtin_amdgcn_mfma_f32_16x16x32_bf16(af[mi][0], bfr[ni][0], c, 0, 0, 0);
                    c = __builtin_amdgcn_mfma_f32_16x16x32_bf16(af[mi][1], bfr[ni][1], c, 0, 0, 0);
                    acc[mh * 4 + mi][nh * 2 + ni] = c;
                }
            __builtin_amdgcn_s_setprio(0);

            if (ph < 3) {
                BAR();
            } else {
                // K-tile boundary: the only vmem drain per tile; loads were issued
                // at this tile's phase 0 (~3 phases of cover). Barrier publishes
                // every wave's staged LDS before anyone reads the new buffer.
                WAIT_VM0();
                BAR();
            }
        }
    }

    // Epilogue: n = ..+l16 (lane-consecutive), m = ..+qd*4+rr (proven mapping).
#pragma unroll
    for (int nf = 0; nf < 4; ++nf) {
        const int n = nBase + wn * 64 + nf * 16 + l16;
        const float bv = bias[n];
#pragma unroll
        for (int mf = 0; mf < 8; ++mf)
#pragma unroll
            for (int rr = 0; rr < 4; ++rr) {
                const int m = mBase + wm * 128 + mf * 16 + qd * 4 + rr;
                C[(size_t)m * N + n] = f2bf(acc[mf][nf][rr] + bv);
            }
    }
}

// GEMM2 (r8 proven component): out = attn @ w_out^T + b_out, f32 out/bias.
// 64x128 tile, BK=32. Grid (8,64) = 512 blocks = 2/CU (12 KB LDS) -> drain overlap.
__global__ __launch_bounds__(256)
void gemm2_out(const short* __restrict__ A, const short* __restrict__ Bt,
               const float* __restrict__ bias, float* __restrict__ C,
               int M, int N, int K) {
    __shared__ short As[64 * 32];    // 4 KB
    __shared__ short Bs[128 * 32];   // 8 KB

    const int tid  = threadIdx.x;
    const int lane = tid & 63;
    const int w    = tid >> 6;
    const int qd   = lane >> 4;
    const int l16  = lane & 15;
    const int wm   = w >> 1;          // 32 rows each
    const int wn   = w & 1;           // 64 cols each
    const int mBase = blockIdx.y * 64;
    const int nBase = blockIdx.x * 128;

    f32x4 acc[2][4] = {};

    const int nK = K >> 5;
    for (int kt = 0; kt < nK; ++kt) {
        const int kb = kt << 5;
        {
            const int e   = tid * 8;            // A: 64x32, one chunk-round
            const int row = e >> 5;
            const int col = e & 31;
            const short* ga = A + (size_t)(mBase + row) * K + kb + col;
            lptr_t la = (lptr_t)(As + w * 512);
            __builtin_amdgcn_global_load_lds((gptr_t)ga, la, 16, 0, 0);
        }
#pragma unroll
        for (int i = 0; i < 2; ++i) {           // B: 128x32
            const int e   = i * 2048 + tid * 8;
            const int row = e >> 5;
            const int col = e & 31;
            const short* gb = Bt + (size_t)(nBase + row) * K + kb + col;
            lptr_t lb = (lptr_t)(Bs + i * 2048 + w * 512);
            __builtin_amdgcn_global_load_lds((gptr_t)gb, lb, 16, 0, 0);
        }
        __syncthreads();

        bf16x8 af[2], bfr[4];
#pragma unroll
        for (int mi = 0; mi < 2; ++mi)
            af[mi] = *(const bf16x8*)(As + (wm * 32 + mi * 16 + l16) * 32 + qd * 8);
#pragma unroll
        for (int ni = 0; ni < 4; ++ni)
            bfr[ni] = *(const bf16x8*)(Bs + (wn * 64 + ni * 16 + l16) * 32 + qd * 8);
#pragma unroll
        for (int mi = 0; mi < 2; ++mi)
#pragma unroll
            for (int ni = 0; ni < 4; ++ni)
                acc[mi][ni] = __builtin_amdgcn_mfma_f32_16x16x32_bf16(
                    af[mi], bfr[ni], acc[mi][ni], 0, 0, 0);
        __syncthreads();
    }

#pragma unroll
    for (int ni = 0; ni < 4; ++ni) {
        const int n = nBase + wn * 64 + ni * 16 + l16;
        const float bv = bias[n];
#pragma unroll
        for (int mi = 0; mi < 2; ++mi)
#pragma unroll
            for (int rr = 0; rr < 4; ++rr) {
                const int m = mBase + wm * 32 + mi * 16 + qd * 4 + rr;
                C[(size_t)m * N + n] = acc[mi][ni][rr] + bv;
            }
    }
}

// MFMA attention (r3, proven). Block = 64 queries x head x batch; 4 waves.
__global__ __launch_bounds__(256)
void attn_mfma(const short* __restrict__ qkv, short* __restrict__ attn_out, int B, int T) {
    __shared__ short k_s[128 * 72];
    __shared__ short v_s[144 * 66];
    __shared__ short p_s[64 * 104];

    const int tid  = threadIdx.x;
    const int lane = tid & 63;
    const int w    = tid >> 6;
    const int qd   = lane >> 4;
    const int l16  = lane & 15;
    const int qs   = blockIdx.x * 64;
    const int h    = blockIdx.y;
    const int b    = blockIdx.z;
    const size_t rs   = 3072;
    const size_t base = (size_t)b * T * rs;
    const int qoff = h * 64, koff = 1024 + h * 64, voff = 2048 + h * 64;

#pragma unroll
    for (int i = 0; i < 5; ++i) {
        const int c   = tid + i * 256;
        const int row = c >> 3;
        if (row >= 144) break;
        const int ch = (c & 7) * 8;
        int gr = qs + row; if (gr > T - 1) gr = T - 1;
        uint4 uv = *(const uint4*)(qkv + base + (size_t)gr * rs + voff + ch);
        if (row < 128) {
            uint4 uk = *(const uint4*)(qkv + base + (size_t)gr * rs + koff + ch);
            *(uint4*)&k_s[row * 72 + ch] = uk;
        }
        const uint32_t* vp = (const uint32_t*)&uv;
        uint32_t* vd = (uint32_t*)&v_s[row * 66 + ch];
        vd[0] = vp[0]; vd[1] = vp[1]; vd[2] = vp[2]; vd[3] = vp[3];
    }
    __syncthreads();

    bf16x8 aq0, aq1;
    {
        const short* g = qkv + base + (size_t)(qs + 16 * w + l16) * rs + qoff + qd * 8;
        aq0 = *(const bf16x8*)(g);
        aq1 = *(const bf16x8*)(g + 32);
    }

    f32x4 sacc[5] = {};
#pragma unroll
    for (int u = 0; u < 5; ++u) {
        const int krow = 16 * (w + u) + l16;
        bf16x8 bk0 = *(const bf16x8*)&k_s[krow * 72 + qd * 8];
        bf16x8 bk1 = *(const bf16x8*)&k_s[krow * 72 + 32 + qd * 8];
        sacc[u] = __builtin_amdgcn_mfma_f32_16x16x32_bf16(aq0, bk0, sacc[u], 0, 0, 0);
        sacc[u] = __builtin_amdgcn_mfma_f32_16x16x32_bf16(aq1, bk1, sacc[u], 0, 0, 0);
    }

    const float scale = 0.125f;
    float pw[5][4];
    float inv[4];
#pragma unroll
    for (int r = 0; r < 4; ++r) {
        const int m = 4 * qd + r;
        float mx = -3.4e38f;
#pragma unroll
        for (int u = 0; u < 5; ++u) {
            const int rel = 16 * u + l16 - m;
            const int j   = qs + 16 * (w + u) + l16;
            const bool ok = (rel >= 0) & (rel <= 64) & (j < T);
            const float v = ok ? sacc[u][r] * scale : -3.4e38f;
            pw[u][r] = v;
            mx = fmaxf(mx, v);
        }
#pragma unroll
        for (int msk = 1; msk <= 8; msk <<= 1) mx = fmaxf(mx, __shfl_xor(mx, msk));
        float sum = 0.f;
#pragma unroll
        for (int u = 0; u < 5; ++u) {
            float e = (pw[u][r] <= -3.0e38f) ? 0.f : __expf(pw[u][r] - mx);
            pw[u][r] = e;
            sum += e;
        }
#pragma unroll
        for (int msk = 1; msk <= 8; msk <<= 1) sum += __shfl_xor(sum, msk);
        inv[r] = 1.0f / sum;
    }

#pragma unroll
    for (int u = 0; u < 5; ++u)
#pragma unroll
        for (int r = 0; r < 4; ++r)
            p_s[(16 * w + 4 * qd + r) * 104 + 16 * u + l16] = f2bf(pw[u][r] * inv[r]);
#pragma unroll
    for (int r = 0; r < 4; ++r)
        p_s[(16 * w + 4 * qd + r) * 104 + 80 + l16] = 0;
    // wave-private rows; same-wave RAW -> lgkmcnt wait, no barrier needed

    f32x4 oacc[4] = {};
#pragma unroll
    for (int ks = 0; ks < 3; ++ks) {
        bf16x8 ap = *(const bf16x8*)&p_s[(16 * w + l16) * 104 + ks * 32 + qd * 8];
#pragma unroll
        for (int dt = 0; dt < 4; ++dt) {
            short t[8];
#pragma unroll
            for (int j = 0; j < 8; ++j)
                t[j] = v_s[(16 * w + ks * 32 + qd * 8 + j) * 66 + 16 * dt + l16];
            bf16x8 bv = *(const bf16x8*)t;
            oacc[dt] = __builtin_amdgcn_mfma_f32_16x16x32_bf16(bv, ap, oacc[dt], 0, 0, 0);
        }
    }

    const size_t row = (size_t)(b * T + qs + 16 * w + l16);
#pragma unroll
    for (int dt = 0; dt < 4; ++dt) {
        short t[4];
#pragma unroll
        for (int r = 0; r < 4; ++r) t[r] = f2bf(oacc[dt][r]);
        *(uint2*)&attn_out[row * 1024 + h * 64 + dt * 16 + qd * 4] = *(const uint2*)t;
    }
}

extern "C" void kernel_launch(void* const* d_in, const int* in_sizes, int n_in,
                              void* d_out, int out_size, void* d_ws, size_t ws_size,
                              hipStream_t stream) {
    (void)in_sizes; (void)n_in; (void)out_size; (void)ws_size;
    const int B = 2, T = 2048, D = 1024;
    const int M = B * T;  // 4096

    char* ws = (char*)d_ws;
    size_t off = 0;
    short* xb   = (short*)(ws + off); off += (size_t)M * D * 2;       // 8.4 MB
    short* wqkb = (short*)(ws + off); off += (size_t)3 * D * D * 2;   // 6.3 MB
    short* wob  = (short*)(ws + off); off += (size_t)D * D * 2;       // 2.1 MB
    short* qkv  = (short*)(ws + off); off += (size_t)M * 3 * D * 2;   // 25.2 MB
    short* attn = (short*)(ws + off); off += (size_t)M * D * 2;       // 8.4 MB

    convert_all<<<dim3(4096), 256, 0, stream>>>(
        (const float*)d_in[0], (const float*)d_in[1], (const float*)d_in[3],
        xb, wqkb, wob);

    gemm1_qkv_8ph<<<dim3(192), 512, 0, stream>>>(
        xb, wqkb, (const float*)d_in[2], qkv, M, 3 * D, D);
    attn_mfma<<<dim3(T / 64, 16, B), 256, 0, stream>>>(qkv, attn, B, T);
    gemm2_out<<<dim3(D / 128, M / 64), 256, 0, stream>>>(
        attn, wob, (const float*)d_in[4], (float*)d_out, M, D, D);
}

// Round 5
// 158.971 us; speedup vs baseline: 1.0339x; 1.0339x over previous
//
#include <hip/hip_runtime.h>
#include <hip/hip_bf16.h>
#include <stdint.h>

// LocalSlidingWindowAttention: B=2, T=2048, D=1024, H=16, hd=64, keys j in [i, i+64].
// f32 in/out. Build:
//   convert_all (r7) -> gemm1_qkv_pipe (256x256, BK=32, 4-deep LDS pipeline,
//   counted vmcnt(8) per tile — T4 proper; r3's 2-buf drain0 variant measured 46us
//   at MfmaUtil 20%, confirming m218 "8ph+drain0 == 1ph")
//   -> attn_mfma (r3, proven) -> gemm2_out (r8, proven).
// Session model: total ~= kernels + ~85us fixed harness overhead.
// gemm1 history: 128^2 m97-structure 43.7us -> 8ph drain0 46.0us -> this: pred ~27us.
// NOTE r4: GPUAcquisitionTimeout; vmcnt ledger + race proofs re-audited, resubmitted.

typedef short bf16x8 __attribute__((ext_vector_type(8)));
typedef float f32x4 __attribute__((ext_vector_type(4)));

typedef const __attribute__((address_space(1))) void* gptr_t;
typedef __attribute__((address_space(3))) void* lptr_t;

#define BAR()        asm volatile("s_barrier" ::: "memory")
#define WAIT_LGKM0() asm volatile("s_waitcnt lgkmcnt(0)" ::: "memory")

__device__ __forceinline__ float bf2f(short u) {
    union { float f; uint32_t i; } x;
    x.i = ((uint32_t)(uint16_t)u) << 16;
    return x.f;
}
__device__ __forceinline__ short f2bf(float f) {
    __hip_bfloat16 h = __float2bfloat16(f);  // RNE
    return *reinterpret_cast<short*>(&h);
}

// Convert x, w_qkv, w_out to bf16. 8 elems/thread.
__global__ __launch_bounds__(256)
void convert_all(const float* __restrict__ x, const float* __restrict__ wq,
                 const float* __restrict__ wo,
                 short* __restrict__ xb, short* __restrict__ wqb, short* __restrict__ wob) {
    int i = blockIdx.x * 256 + threadIdx.x;
    const float* src; short* dst; int o;
    if      (i <  524288) { src = x;  dst = xb;  o = i; }
    else if (i <  917504) { src = wq; dst = wqb; o = i - 524288; }
    else                  { src = wo; dst = wob; o = i - 917504; }
    const int e = o * 8;
    float4 a = *(const float4*)(src + e);
    float4 b = *(const float4*)(src + e + 4);
    short t[8];
    t[0] = f2bf(a.x); t[1] = f2bf(a.y); t[2] = f2bf(a.z); t[3] = f2bf(a.w);
    t[4] = f2bf(b.x); t[5] = f2bf(b.y); t[6] = f2bf(b.z); t[7] = f2bf(b.w);
    *(uint4*)(dst + e) = *(const uint4*)t;
}

// GEMM1, 256x256 tile, BK=32, 4-deep counted-vmcnt pipeline (T3+T4).
// 512 threads = 8 waves (2M x 4N), per-wave output 128x64, acc[8][4].
// LDS: 4 buffers x (256x32 A + 256x32 B) = 128 KiB. Per K-tile (2 phases x 16 MFMA):
//   ph0: ds_read af[0..3]+bfr[0..3]; issue 2 gload_lds (tile kt+3, A); BAR; lgkm0;
//        MFMA m0-3 x n0-3; BAR.
//   ph1: ds_read af[4..7]; issue 2 gload_lds (tile kt+3, B); BAR; lgkm0;
//        MFMA m4-7 x n0-3; vmcnt(8) [retires ONLY tile kt+1's 4 loads, issued 3
//        tiles (~6 phases) earlier -> latency covered, never drain to 0]; BAR.
// Tail peel: vmcnt(4) then vmcnt(0) then no-wait (counts exact, see retire math).
// No LDS swizzle needed at BK=32: 64B row stride -> each bank serves exactly 8
// lanes = the b128 throughput floor (1024B / 128B-per-clock); conflict-free linear.
// Buffer reuse proof: tile kt+3 -> buf (kt-1)&3; its readers lgkm-drained before
// tile kt-1's last MFMA and crossed the kt-1 boundary BAR preceding this issue.
__global__ __launch_bounds__(512, 1)
void gemm1_qkv_pipe(const short* __restrict__ A, const short* __restrict__ Bt,
                    const float* __restrict__ bias, short* __restrict__ C,
                    int M, int N, int K) {
    __shared__ short As[4][256 * 32];   // 64 KiB
    __shared__ short Bs[4][256 * 32];   // 64 KiB

    const int tid  = threadIdx.x;
    const int lane = tid & 63;
    const int w    = tid >> 6;        // 0..7
    const int qd   = lane >> 4;       // 0..3
    const int l16  = lane & 15;
    const int wm   = w >> 2;          // 0..1  (128 rows each)
    const int wn   = w & 3;          // 0..3  (64 cols each)

    // XCD-chunked bijective swizzle (nwg=192, 192%8==0): XCD g gets 24 contiguous
    // wg = 2 m-panels x all 12 n-tiles -> A-panel L2 reuse.
    const int nTn   = N >> 8;                     // 12
    const int chunk = gridDim.x >> 3;             // 24
    const int wg    = (blockIdx.x & 7) * chunk + (blockIdx.x >> 3);
    const int mt    = wg / nTn;
    const int nt    = wg - mt * nTn;
    const int mBase = mt << 8;
    const int nBase = nt << 8;

    // Staging sources: tile = 256 rows x 32 cols = 1024 granules of 16B.
    // granule g = rr*512 + tid: row = g>>2, slot = g&3 (8-col chunk). Linear both
    // sides (no swizzle). LDS dest short-offset = g*8 = row*32 + slot*8 == read addr.
    const short* gA[2];
    const short* gB[2];
#pragma unroll
    for (int rr = 0; rr < 2; ++rr) {
        const int g    = rr * 512 + tid;
        const int row  = g >> 2;
        const int slot = g & 3;
        gA[rr] = A  + (size_t)(mBase + row) * K + slot * 8;
        gB[rr] = Bt + (size_t)(nBase + row) * K + slot * 8;
    }

    f32x4 acc[8][4] = {};
    const int nk = K >> 5;                        // 32 (requires nk >= 4)

    // Prologue: stage tiles 0,1,2 (strict tile order for vmcnt retire math).
#pragma unroll
    for (int t = 0; t < 3; ++t) {
#pragma unroll
        for (int rr = 0; rr < 2; ++rr)
            __builtin_amdgcn_global_load_lds((gptr_t)(gA[rr] + (size_t)t * 32),
                (lptr_t)(&As[t][0] + (rr * 512 + w * 64) * 8), 16, 0, 0);
#pragma unroll
        for (int rr = 0; rr < 2; ++rr)
            __builtin_amdgcn_global_load_lds((gptr_t)(gB[rr] + (size_t)t * 32),
                (lptr_t)(&Bs[t][0] + (rr * 512 + w * 64) * 8), 16, 0, 0);
    }
    asm volatile("s_waitcnt vmcnt(8)" ::: "memory");   // retire tile 0 (12 -> 8)
    BAR();

#define TILE_BODY(KT, DO_ISSUE, ENDWAIT)                                          \
    {                                                                             \
        const int cur_ = (KT) & 3;                                                \
        const short* Ab_ = &As[cur_][0];                                          \
        const short* Bb_ = &Bs[cur_][0];                                          \
        bf16x8 af0_[4], bfr_[4];                                                  \
        _Pragma("unroll")                                                         \
        for (int mi = 0; mi < 4; ++mi) {                                          \
            const int row = wm * 128 + mi * 16 + l16;                             \
            af0_[mi] = *(const bf16x8*)(Ab_ + row * 32 + qd * 8);                 \
        }                                                                         \
        _Pragma("unroll")                                                         \
        for (int ni = 0; ni < 4; ++ni) {                                          \
            const int row = wn * 64 + ni * 16 + l16;                              \
            bfr_[ni] = *(const bf16x8*)(Bb_ + row * 32 + qd * 8);                 \
        }                                                                         \
        if (DO_ISSUE) {                                                           \
            const int nb_ = ((KT) + 3) & 3;                                       \
            const size_t kadv_ = (size_t)((KT) + 3) * 32;                         \
            _Pragma("unroll")                                                     \
            for (int rr = 0; rr < 2; ++rr)                                        \
                __builtin_amdgcn_global_load_lds((gptr_t)(gA[rr] + kadv_),        \
                    (lptr_t)(&As[nb_][0] + (rr * 512 + w * 64) * 8), 16, 0, 0);   \
        }                                                                         \
        BAR(); WAIT_LGKM0(); __builtin_amdgcn_sched_barrier(0);                   \
        __builtin_amdgcn_s_setprio(1);                                            \
        _Pragma("unroll")                                                         \
        for (int mi = 0; mi < 4; ++mi)                                            \
            _Pragma("unroll")                                                     \
            for (int ni = 0; ni < 4; ++ni)                                        \
                acc[mi][ni] = __builtin_amdgcn_mfma_f32_16x16x32_bf16(            \
                    af0_[mi], bfr_[ni], acc[mi][ni], 0, 0, 0);                    \
        __builtin_amdgcn_s_setprio(0);                                            \
        BAR();                                                                    \
        bf16x8 af1_[4];                                                           \
        _Pragma("unroll")                                                         \
        for (int mi = 0; mi < 4; ++mi) {                                          \
            const int row = wm * 128 + 64 + mi * 16 + l16;                        \
            af1_[mi] = *(const bf16x8*)(Ab_ + row * 32 + qd * 8);                 \
        }                                                                         \
        if (DO_ISSUE) {                                                           \
            const int nb_ = ((KT) + 3) & 3;                                       \
            const size_t kadv_ = (size_t)((KT) + 3) * 32;                         \
            _Pragma("unroll")                                                     \
            for (int rr = 0; rr < 2; ++rr)                                        \
                __builtin_amdgcn_global_load_lds((gptr_t)(gB[rr] + kadv_),        \
                    (lptr_t)(&Bs[nb_][0] + (rr * 512 + w * 64) * 8), 16, 0, 0);   \
        }                                                                         \
        BAR(); WAIT_LGKM0(); __builtin_amdgcn_sched_barrier(0);                   \
        __builtin_amdgcn_s_setprio(1);                                            \
        _Pragma("unroll")                                                         \
        for (int mi = 0; mi < 4; ++mi)                                            \
            _Pragma("unroll")                                                     \
            for (int ni = 0; ni < 4; ++ni)                                        \
                acc[mi + 4][ni] = __builtin_amdgcn_mfma_f32_16x16x32_bf16(        \
                    af1_[mi], bfr_[ni], acc[mi + 4][ni], 0, 0, 0);                \
        __builtin_amdgcn_s_setprio(0);                                            \
        ENDWAIT;                                                                  \
        BAR();                                                                    \
    }

    // Main: tiles 0..nk-4 issue tile kt+3 and retire tile kt+1 with vmcnt(8)
    // (outstanding at wait = kt+1,kt+2,kt+3 = 12 loads -> oldest 4 retired).
    for (int kt = 0; kt < nk - 3; ++kt)
        TILE_BODY(kt, 1, asm volatile("s_waitcnt vmcnt(8)" ::: "memory"))
    // Tail: nk-3 (outstanding 8 -> vmcnt(4) retires nk-2), nk-2 (4 -> vmcnt(0)
    // retires nk-1), nk-1 (nothing outstanding, no wait).
    TILE_BODY(nk - 3, 0, asm volatile("s_waitcnt vmcnt(4)" ::: "memory"))
    TILE_BODY(nk - 2, 0, asm volatile("s_waitcnt vmcnt(0)" ::: "memory"))
    TILE_BODY(nk - 1, 0, (void)0)
#undef TILE_BODY

    // Epilogue: n = ..+l16 (lane-consecutive), m = ..+qd*4+rr (proven mapping).
#pragma unroll
    for (int nf = 0; nf < 4; ++nf) {
        const int n = nBase + wn * 64 + nf * 16 + l16;
        const float bv = bias[n];
#pragma unroll
        for (int mf = 0; mf < 8; ++mf)
#pragma unroll
            for (int rr = 0; rr < 4; ++rr) {
                const int m = mBase + wm * 128 + mf * 16 + qd * 4 + rr;
                C[(size_t)m * N + n] = f2bf(acc[mf][nf][rr] + bv);
            }
    }
}

// GEMM2 (r8 proven component): out = attn @ w_out^T + b_out, f32 out/bias.
// 64x128 tile, BK=32. Grid (8,64) = 512 blocks = 2/CU (12 KB LDS) -> drain overlap.
__global__ __launch_bounds__(256)
void gemm2_out(const short* __restrict__ A, const short* __restrict__ Bt,
               const float* __restrict__ bias, float* __restrict__ C,
               int M, int N, int K) {
    __shared__ short As[64 * 32];    // 4 KB
    __shared__ short Bs[128 * 32];   // 8 KB

    const int tid  = threadIdx.x;
    const int lane = tid & 63;
    const int w    = tid >> 6;
    const int qd   = lane >> 4;
    const int l16  = lane & 15;
    const int wm   = w >> 1;          // 32 rows each
    const int wn   = w & 1;           // 64 cols each
    const int mBase = blockIdx.y * 64;
    const int nBase = blockIdx.x * 128;

    f32x4 acc[2][4] = {};

    const int nK = K >> 5;
    for (int kt = 0; kt < nK; ++kt) {
        const int kb = kt << 5;
        {
            const int e   = tid * 8;            // A: 64x32, one chunk-round
            const int row = e >> 5;
            const int col = e & 31;
            const short* ga = A + (size_t)(mBase + row) * K + kb + col;
            lptr_t la = (lptr_t)(As + w * 512);
            __builtin_amdgcn_global_load_lds((gptr_t)ga, la, 16, 0, 0);
        }
#pragma unroll
        for (int i = 0; i < 2; ++i) {           // B: 128x32
            const int e   = i * 2048 + tid * 8;
            const int row = e >> 5;
            const int col = e & 31;
            const short* gb = Bt + (size_t)(nBase + row) * K + kb + col;
            lptr_t lb = (lptr_t)(Bs + i * 2048 + w * 512);
            __builtin_amdgcn_global_load_lds((gptr_t)gb, lb, 16, 0, 0);
        }
        __syncthreads();

        bf16x8 af[2], bfr[4];
#pragma unroll
        for (int mi = 0; mi < 2; ++mi)
            af[mi] = *(const bf16x8*)(As + (wm * 32 + mi * 16 + l16) * 32 + qd * 8);
#pragma unroll
        for (int ni = 0; ni < 4; ++ni)
            bfr[ni] = *(const bf16x8*)(Bs + (wn * 64 + ni * 16 + l16) * 32 + qd * 8);
#pragma unroll
        for (int mi = 0; mi < 2; ++mi)
#pragma unroll
            for (int ni = 0; ni < 4; ++ni)
                acc[mi][ni] = __builtin_amdgcn_mfma_f32_16x16x32_bf16(
                    af[mi], bfr[ni], acc[mi][ni], 0, 0, 0);
        __syncthreads();
    }

#pragma unroll
    for (int ni = 0; ni < 4; ++ni) {
        const int n = nBase + wn * 64 + ni * 16 + l16;
        const float bv = bias[n];
#pragma unroll
        for (int mi = 0; mi < 2; ++mi)
#pragma unroll
            for (int rr = 0; rr < 4; ++rr) {
                const int m = mBase + wm * 32 + mi * 16 + qd * 4 + rr;
                C[(size_t)m * N + n] = acc[mi][ni][rr] + bv;
            }
    }
}

// MFMA attention (r3, proven). Block = 64 queries x head x batch; 4 waves.
__global__ __launch_bounds__(256)
void attn_mfma(const short* __restrict__ qkv, short* __restrict__ attn_out, int B, int T) {
    __shared__ short k_s[128 * 72];
    __shared__ short v_s[144 * 66];
    __shared__ short p_s[64 * 104];

    const int tid  = threadIdx.x;
    const int lane = tid & 63;
    const int w    = tid >> 6;
    const int qd   = lane >> 4;
    const int l16  = lane & 15;
    const int qs   = blockIdx.x * 64;
    const int h    = blockIdx.y;
    const int b    = blockIdx.z;
    const size_t rs   = 3072;
    const size_t base = (size_t)b * T * rs;
    const int qoff = h * 64, koff = 1024 + h * 64, voff = 2048 + h * 64;

#pragma unroll
    for (int i = 0; i < 5; ++i) {
        const int c   = tid + i * 256;
        const int row = c >> 3;
        if (row >= 144) break;
        const int ch = (c & 7) * 8;
        int gr = qs + row; if (gr > T - 1) gr = T - 1;
        uint4 uv = *(const uint4*)(qkv + base + (size_t)gr * rs + voff + ch);
        if (row < 128) {
            uint4 uk = *(const uint4*)(qkv + base + (size_t)gr * rs + koff + ch);
            *(uint4*)&k_s[row * 72 + ch] = uk;
        }
        const uint32_t* vp = (const uint32_t*)&uv;
        uint32_t* vd = (uint32_t*)&v_s[row * 66 + ch];
        vd[0] = vp[0]; vd[1] = vp[1]; vd[2] = vp[2]; vd[3] = vp[3];
    }
    __syncthreads();

    bf16x8 aq0, aq1;
    {
        const short* g = qkv + base + (size_t)(qs + 16 * w + l16) * rs + qoff + qd * 8;
        aq0 = *(const bf16x8*)(g);
        aq1 = *(const bf16x8*)(g + 32);
    }

    f32x4 sacc[5] = {};
#pragma unroll
    for (int u = 0; u < 5; ++u) {
        const int krow = 16 * (w + u) + l16;
        bf16x8 bk0 = *(const bf16x8*)&k_s[krow * 72 + qd * 8];
        bf16x8 bk1 = *(const bf16x8*)&k_s[krow * 72 + 32 + qd * 8];
        sacc[u] = __builtin_amdgcn_mfma_f32_16x16x32_bf16(aq0, bk0, sacc[u], 0, 0, 0);
        sacc[u] = __builtin_amdgcn_mfma_f32_16x16x32_bf16(aq1, bk1, sacc[u], 0, 0, 0);
    }

    const float scale = 0.125f;
    float pw[5][4];
    float inv[4];
#pragma unroll
    for (int r = 0; r < 4; ++r) {
        const int m = 4 * qd + r;
        float mx = -3.4e38f;
#pragma unroll
        for (int u = 0; u < 5; ++u) {
            const int rel = 16 * u + l16 - m;
            const int j   = qs + 16 * (w + u) + l16;
            const bool ok = (rel >= 0) & (rel <= 64) & (j < T);
            const float v = ok ? sacc[u][r] * scale : -3.4e38f;
            pw[u][r] = v;
            mx = fmaxf(mx, v);
        }
#pragma unroll
        for (int msk = 1; msk <= 8; msk <<= 1) mx = fmaxf(mx, __shfl_xor(mx, msk));
        float sum = 0.f;
#pragma unroll
        for (int u = 0; u < 5; ++u) {
            float e = (pw[u][r] <= -3.0e38f) ? 0.f : __expf(pw[u][r] - mx);
            pw[u][r] = e;
            sum += e;
        }
#pragma unroll
        for (int msk = 1; msk <= 8; msk <<= 1) sum += __shfl_xor(sum, msk);
        inv[r] = 1.0f / sum;
    }

#pragma unroll
    for (int u = 0; u < 5; ++u)
#pragma unroll
        for (int r = 0; r < 4; ++r)
            p_s[(16 * w + 4 * qd + r) * 104 + 16 * u + l16] = f2bf(pw[u][r] * inv[r]);
#pragma unroll
    for (int r = 0; r < 4; ++r)
        p_s[(16 * w + 4 * qd + r) * 104 + 80 + l16] = 0;
    // wave-private rows; same-wave RAW -> lgkmcnt wait, no barrier needed

    f32x4 oacc[4] = {};
#pragma unroll
    for (int ks = 0; ks < 3; ++ks) {
        bf16x8 ap = *(const bf16x8*)&p_s[(16 * w + l16) * 104 + ks * 32 + qd * 8];
#pragma unroll
        for (int dt = 0; dt < 4; ++dt) {
            short t[8];
#pragma unroll
            for (int j = 0; j < 8; ++j)
                t[j] = v_s[(16 * w + ks * 32 + qd * 8 + j) * 66 + 16 * dt + l16];
            bf16x8 bv = *(const bf16x8*)t;
            oacc[dt] = __builtin_amdgcn_mfma_f32_16x16x32_bf16(bv, ap, oacc[dt], 0, 0, 0);
        }
    }

    const size_t row = (size_t)(b * T + qs + 16 * w + l16);
#pragma unroll
    for (int dt = 0; dt < 4; ++dt) {
        short t[4];
#pragma unroll
        for (int r = 0; r < 4; ++r) t[r] = f2bf(oacc[dt][r]);
        *(uint2*)&attn_out[row * 1024 + h * 64 + dt * 16 + qd * 4] = *(const uint2*)t;
    }
}

extern "C" void kernel_launch(void* const* d_in, const int* in_sizes, int n_in,
                              void* d_out, int out_size, void* d_ws, size_t ws_size,
                              hipStream_t stream) {
    (void)in_sizes; (void)n_in; (void)out_size; (void)ws_size;
    const int B = 2, T = 2048, D = 1024;
    const int M = B * T;  // 4096

    char* ws = (char*)d_ws;
    size_t off = 0;
    short* xb   = (short*)(ws + off); off += (size_t)M * D * 2;       // 8.4 MB
    short* wqkb = (short*)(ws + off); off += (size_t)3 * D * D * 2;   // 6.3 MB
    short* wob  = (short*)(ws + off); off += (size_t)D * D * 2;       // 2.1 MB
    short* qkv  = (short*)(ws + off); off += (size_t)M * 3 * D * 2;   // 25.2 MB
    short* attn = (short*)(ws + off); off += (size_t)M * D * 2;       // 8.4 MB

    convert_all<<<dim3(4096), 256, 0, stream>>>(
        (const float*)d_in[0], (const float*)d_in[1], (const float*)d_in[3],
        xb, wqkb, wob);

    gemm1_qkv_pipe<<<dim3(192), 512, 0, stream>>>(
        xb, wqkb, (const float*)d_in[2], qkv, M, 3 * D, D);
    attn_mfma<<<dim3(T / 64, 16, B), 256, 0, stream>>>(qkv, attn, B, T);
    gemm2_out<<<dim3(D / 128, M / 64), 256, 0, stream>>>(
        attn, wob, (const float*)d_in[4], (float*)d_out, M, D, D);
}

// Round 6
// 152.544 us; speedup vs baseline: 1.0774x; 1.0421x over previous
//
#include <hip/hip_runtime.h>
#include <hip/hip_bf16.h>
#include <stdint.h>

// LocalSlidingWindowAttention: B=2, T=2048, D=1024, H=16, hd=64, keys j in [i, i+64].
// f32 in/out. Build:
//   convert_all (r7) -> gemm1_qkv_pipe (r6: 256x256, BK=32, 4-deep counted-vmcnt
//   pipeline + ONE barrier per tile (wave-drift overlap) + XOR bank swizzle)
//   -> attn_mfma (r3, proven) -> gemm2_out (r8, proven).
// gemm1 history: 128^2 m97 43.7us -> 8ph drain0 46.0 -> 4-deep counted 42.3
//   (MfmaUtil 21%, BANK_CONFLICT 2.36M = 4cyc/b128, LDS-read-bound at 27% of bound;
//   lockstep 4-barriers/tile blocked cross-wave LDS/MFMA overlap).
// r6: barriers 4->1 per tile (correctness needs only the boundary BAR: per-wave
//   lgkm waits cover reads, ENDWAIT ledger + boundary BAR covers staging), split
//   lgkmcnt(4)/lgkmcnt(0) waits, swizzle slot = qd ^ ((row>>1)&3) both-sides.

typedef short bf16x8 __attribute__((ext_vector_type(8)));
typedef float f32x4 __attribute__((ext_vector_type(4)));

typedef const __attribute__((address_space(1))) void* gptr_t;
typedef __attribute__((address_space(3))) void* lptr_t;

#define BAR()        asm volatile("s_barrier" ::: "memory")
#define WAIT_LGKM0() asm volatile("s_waitcnt lgkmcnt(0)" ::: "memory")

__device__ __forceinline__ float bf2f(short u) {
    union { float f; uint32_t i; } x;
    x.i = ((uint32_t)(uint16_t)u) << 16;
    return x.f;
}
__device__ __forceinline__ short f2bf(float f) {
    __hip_bfloat16 h = __float2bfloat16(f);  // RNE
    return *reinterpret_cast<short*>(&h);
}

// Convert x, w_qkv, w_out to bf16. 8 elems/thread.
__global__ __launch_bounds__(256)
void convert_all(const float* __restrict__ x, const float* __restrict__ wq,
                 const float* __restrict__ wo,
                 short* __restrict__ xb, short* __restrict__ wqb, short* __restrict__ wob) {
    int i = blockIdx.x * 256 + threadIdx.x;
    const float* src; short* dst; int o;
    if      (i <  524288) { src = x;  dst = xb;  o = i; }
    else if (i <  917504) { src = wq; dst = wqb; o = i - 524288; }
    else                  { src = wo; dst = wob; o = i - 917504; }
    const int e = o * 8;
    float4 a = *(const float4*)(src + e);
    float4 b = *(const float4*)(src + e + 4);
    short t[8];
    t[0] = f2bf(a.x); t[1] = f2bf(a.y); t[2] = f2bf(a.z); t[3] = f2bf(a.w);
    t[4] = f2bf(b.x); t[5] = f2bf(b.y); t[6] = f2bf(b.z); t[7] = f2bf(b.w);
    *(uint4*)(dst + e) = *(const uint4*)t;
}

// GEMM1, 256x256 tile, BK=32, 4-deep counted-vmcnt pipeline, 1 barrier/tile.
// 512 threads = 8 waves (2M x 4N), per-wave output 128x64, acc[8][4].
// LDS: 4 buffers x (256x32 A + 256x32 B) = 128 KiB.
// Per K-tile: {12 ds_read (af0,bfr | af1) split by sched_barrier; issue 4 gloads
// for tile kt+3; lgkmcnt(4); 16 MFMA; lgkmcnt(0); 16 MFMA; vmcnt(8); s_barrier}.
// Waves drift within the tile body -> one wave's ds_reads overlap another's MFMAs
// on the same SIMD (LDS pipe and MFMA pipe both stay fed).
// vmcnt ledger (4 loads/tile, strict order): at ENDWAIT of kt, outstanding =
// kt+1,kt+2,kt+3 (12) -> vmcnt(8) retires exactly kt+1 (issued 3 tiles ago).
// Tail: vmcnt(4), vmcnt(0), none.
// Bank swizzle (both-sides, rule #21): LDS[row][slot] holds global chunk
// slot^((row>>1)&3); read slot qd^((row>>1)&3). Row-bases are mult of 16 ->
// read slot = qd ^ ((l16>>1)&3) = per-thread constant sx (zero VALU cost).
// Bank quads: q = 4*(row&1) + slot -> 2 lanes/quad per quarter-wave = free (m136).
// Race safety (1 barrier): any wave in tile kt body implies ALL waves passed the
// kt-1 boundary BAR, i.e. finished their kt-1 reads (lgkm-drained pre-MFMA) and
// their ENDWAIT (own loads for kt landed). So staging into buf (kt-1)&3 is safe
// and reads of buf kt&3 see all waves' staged data.
__global__ __launch_bounds__(512, 1)
void gemm1_qkv_pipe(const short* __restrict__ A, const short* __restrict__ Bt,
                    const float* __restrict__ bias, short* __restrict__ C,
                    int M, int N, int K) {
    __shared__ short As[4][256 * 32];   // 64 KiB
    __shared__ short Bs[4][256 * 32];   // 64 KiB

    const int tid  = threadIdx.x;
    const int lane = tid & 63;
    const int w    = tid >> 6;        // 0..7
    const int qd   = lane >> 4;       // 0..3
    const int l16  = lane & 15;
    const int wm   = w >> 2;          // 0..1  (128 rows each)
    const int wn   = w & 3;           // 0..3  (64 cols each)
    const int sx8  = (qd ^ ((l16 >> 1) & 3)) * 8;   // swizzled read slot (shorts)

    // XCD-chunked bijective swizzle (nwg=192, 192%8==0): XCD g gets 24 contiguous
    // wg = 2 m-panels x all 12 n-tiles -> A-panel L2 reuse.
    const int nTn   = N >> 8;                     // 12
    const int chunk = gridDim.x >> 3;             // 24
    const int wg    = (blockIdx.x & 7) * chunk + (blockIdx.x >> 3);
    const int mt    = wg / nTn;
    const int nt    = wg - mt * nTn;
    const int mBase = mt << 8;
    const int nBase = nt << 8;

    // Staging sources: tile = 256 rows x 32 cols = 1024 granules of 16B.
    // granule g = rr*512 + tid: row = g>>2, stored slot = g&3; source chunk is
    // pre-XOR'd: (g&3) ^ ((g>>3)&3) so LDS[row][slot] holds chunk slot^((row>>1)&3).
    const short* gA[2];
    const short* gB[2];
#pragma unroll
    for (int rr = 0; rr < 2; ++rr) {
        const int g    = rr * 512 + tid;
        const int row  = g >> 2;
        const int slot = (g & 3) ^ ((g >> 3) & 3);
        gA[rr] = A  + (size_t)(mBase + row) * K + slot * 8;
        gB[rr] = Bt + (size_t)(nBase + row) * K + slot * 8;
    }

    f32x4 acc[8][4] = {};
    const int nk = K >> 5;                        // 32 (requires nk >= 4)

    // Prologue: stage tiles 0,1,2 (strict tile order for vmcnt retire math).
#pragma unroll
    for (int t = 0; t < 3; ++t) {
#pragma unroll
        for (int rr = 0; rr < 2; ++rr)
            __builtin_amdgcn_global_load_lds((gptr_t)(gA[rr] + (size_t)t * 32),
                (lptr_t)(&As[t][0] + (rr * 512 + w * 64) * 8), 16, 0, 0);
#pragma unroll
        for (int rr = 0; rr < 2; ++rr)
            __builtin_amdgcn_global_load_lds((gptr_t)(gB[rr] + (size_t)t * 32),
                (lptr_t)(&Bs[t][0] + (rr * 512 + w * 64) * 8), 16, 0, 0);
    }
    asm volatile("s_waitcnt vmcnt(8)" ::: "memory");   // retire tile 0 (12 -> 8)
    BAR();

#define TILE_BODY(KT, DO_ISSUE, ENDWAIT)                                          \
    {                                                                             \
        const int cur_ = (KT) & 3;                                                \
        const short* Ab_ = &As[cur_][0];                                          \
        const short* Bb_ = &Bs[cur_][0];                                          \
        bf16x8 af0_[4], bfr_[4], af1_[4];                                         \
        _Pragma("unroll")                                                         \
        for (int mi = 0; mi < 4; ++mi)                                            \
            af0_[mi] = *(const bf16x8*)(Ab_ + (wm * 128 + mi * 16 + l16) * 32 + sx8); \
        _Pragma("unroll")                                                         \
        for (int ni = 0; ni < 4; ++ni)                                            \
            bfr_[ni] = *(const bf16x8*)(Bb_ + (wn * 64 + ni * 16 + l16) * 32 + sx8);  \
        __builtin_amdgcn_sched_barrier(0); /* pin: first 8 reads before af1 */    \
        _Pragma("unroll")                                                         \
        for (int mi = 0; mi < 4; ++mi)                                            \
            af1_[mi] = *(const bf16x8*)(Ab_ + (wm * 128 + 64 + mi * 16 + l16) * 32 + sx8); \
        if (DO_ISSUE) {                                                           \
            const int nb_ = ((KT) + 3) & 3;                                       \
            const size_t kadv_ = (size_t)((KT) + 3) * 32;                         \
            _Pragma("unroll")                                                     \
            for (int rr = 0; rr < 2; ++rr)                                        \
                __builtin_amdgcn_global_load_lds((gptr_t)(gA[rr] + kadv_),        \
                    (lptr_t)(&As[nb_][0] + (rr * 512 + w * 64) * 8), 16, 0, 0);   \
            _Pragma("unroll")                                                     \
            for (int rr = 0; rr < 2; ++rr)                                        \
                __builtin_amdgcn_global_load_lds((gptr_t)(gB[rr] + kadv_),        \
                    (lptr_t)(&Bs[nb_][0] + (rr * 512 + w * 64) * 8), 16, 0, 0);   \
        }                                                                         \
        asm volatile("s_waitcnt lgkmcnt(4)" ::: "memory"); /* af0+bfr landed */   \
        __builtin_amdgcn_sched_barrier(0);                                        \
        __builtin_amdgcn_s_setprio(1);                                            \
        _Pragma("unroll")                                                         \
        for (int mi = 0; mi < 4; ++mi)                                            \
            _Pragma("unroll")                                                     \
            for (int ni = 0; ni < 4; ++ni)                                        \
                acc[mi][ni] = __builtin_amdgcn_mfma_f32_16x16x32_bf16(            \
                    af0_[mi], bfr_[ni], acc[mi][ni], 0, 0, 0);                    \
        __builtin_amdgcn_s_setprio(0);                                            \
        WAIT_LGKM0();                                                             \
        __builtin_amdgcn_sched_barrier(0);                                        \
        __builtin_amdgcn_s_setprio(1);                                            \
        _Pragma("unroll")                                                         \
        for (int mi = 0; mi < 4; ++mi)                                            \
            _Pragma("unroll")                                                     \
            for (int ni = 0; ni < 4; ++ni)                                        \
                acc[mi + 4][ni] = __builtin_amdgcn_mfma_f32_16x16x32_bf16(        \
                    af1_[mi], bfr_[ni], acc[mi + 4][ni], 0, 0, 0);                \
        __builtin_amdgcn_s_setprio(0);                                            \
        ENDWAIT;                                                                  \
        BAR();                                                                    \
    }

    // Main: tiles 0..nk-4 issue tile kt+3 and retire tile kt+1 with vmcnt(8).
    for (int kt = 0; kt < nk - 3; ++kt)
        TILE_BODY(kt, 1, asm volatile("s_waitcnt vmcnt(8)" ::: "memory"))
    // Tail: nk-3 (8 outstanding -> vmcnt(4) retires nk-2), nk-2 (vmcnt(0)), nk-1.
    TILE_BODY(nk - 3, 0, asm volatile("s_waitcnt vmcnt(4)" ::: "memory"))
    TILE_BODY(nk - 2, 0, asm volatile("s_waitcnt vmcnt(0)" ::: "memory"))
    TILE_BODY(nk - 1, 0, (void)0)
#undef TILE_BODY

    // Epilogue: n = ..+l16 (lane-consecutive), m = ..+qd*4+rr (proven mapping).
#pragma unroll
    for (int nf = 0; nf < 4; ++nf) {
        const int n = nBase + wn * 64 + nf * 16 + l16;
        const float bv = bias[n];
#pragma unroll
        for (int mf = 0; mf < 8; ++mf)
#pragma unroll
            for (int rr = 0; rr < 4; ++rr) {
                const int m = mBase + wm * 128 + mf * 16 + qd * 4 + rr;
                C[(size_t)m * N + n] = f2bf(acc[mf][nf][rr] + bv);
            }
    }
}

// GEMM2 (r8 proven component): out = attn @ w_out^T + b_out, f32 out/bias.
// 64x128 tile, BK=32. Grid (8,64) = 512 blocks = 2/CU (12 KB LDS) -> drain overlap.
__global__ __launch_bounds__(256)
void gemm2_out(const short* __restrict__ A, const short* __restrict__ Bt,
               const float* __restrict__ bias, float* __restrict__ C,
               int M, int N, int K) {
    __shared__ short As[64 * 32];    // 4 KB
    __shared__ short Bs[128 * 32];   // 8 KB

    const int tid  = threadIdx.x;
    const int lane = tid & 63;
    const int w    = tid >> 6;
    const int qd   = lane >> 4;
    const int l16  = lane & 15;
    const int wm   = w >> 1;          // 32 rows each
    const int wn   = w & 1;           // 64 cols each
    const int mBase = blockIdx.y * 64;
    const int nBase = blockIdx.x * 128;

    f32x4 acc[2][4] = {};

    const int nK = K >> 5;
    for (int kt = 0; kt < nK; ++kt) {
        const int kb = kt << 5;
        {
            const int e   = tid * 8;            // A: 64x32, one chunk-round
            const int row = e >> 5;
            const int col = e & 31;
            const short* ga = A + (size_t)(mBase + row) * K + kb + col;
            lptr_t la = (lptr_t)(As + w * 512);
            __builtin_amdgcn_global_load_lds((gptr_t)ga, la, 16, 0, 0);
        }
#pragma unroll
        for (int i = 0; i < 2; ++i) {           // B: 128x32
            const int e   = i * 2048 + tid * 8;
            const int row = e >> 5;
            const int col = e & 31;
            const short* gb = Bt + (size_t)(nBase + row) * K + kb + col;
            lptr_t lb = (lptr_t)(Bs + i * 2048 + w * 512);
            __builtin_amdgcn_global_load_lds((gptr_t)gb, lb, 16, 0, 0);
        }
        __syncthreads();

        bf16x8 af[2], bfr[4];
#pragma unroll
        for (int mi = 0; mi < 2; ++mi)
            af[mi] = *(const bf16x8*)(As + (wm * 32 + mi * 16 + l16) * 32 + qd * 8);
#pragma unroll
        for (int ni = 0; ni < 4; ++ni)
            bfr[ni] = *(const bf16x8*)(Bs + (wn * 64 + ni * 16 + l16) * 32 + qd * 8);
#pragma unroll
        for (int mi = 0; mi < 2; ++mi)
#pragma unroll
            for (int ni = 0; ni < 4; ++ni)
                acc[mi][ni] = __builtin_amdgcn_mfma_f32_16x16x32_bf16(
                    af[mi], bfr[ni], acc[mi][ni], 0, 0, 0);
        __syncthreads();
    }

#pragma unroll
    for (int ni = 0; ni < 4; ++ni) {
        const int n = nBase + wn * 64 + ni * 16 + l16;
        const float bv = bias[n];
#pragma unroll
        for (int mi = 0; mi < 2; ++mi)
#pragma unroll
            for (int rr = 0; rr < 4; ++rr) {
                const int m = mBase + wm * 32 + mi * 16 + qd * 4 + rr;
                C[(size_t)m * N + n] = acc[mi][ni][rr] + bv;
            }
    }
}

// MFMA attention (r3, proven). Block = 64 queries x head x batch; 4 waves.
__global__ __launch_bounds__(256)
void attn_mfma(const short* __restrict__ qkv, short* __restrict__ attn_out, int B, int T) {
    __shared__ short k_s[128 * 72];
    __shared__ short v_s[144 * 66];
    __shared__ short p_s[64 * 104];

    const int tid  = threadIdx.x;
    const int lane = tid & 63;
    const int w    = tid >> 6;
    const int qd   = lane >> 4;
    const int l16  = lane & 15;
    const int qs   = blockIdx.x * 64;
    const int h    = blockIdx.y;
    const int b    = blockIdx.z;
    const size_t rs   = 3072;
    const size_t base = (size_t)b * T * rs;
    const int qoff = h * 64, koff = 1024 + h * 64, voff = 2048 + h * 64;

#pragma unroll
    for (int i = 0; i < 5; ++i) {
        const int c   = tid + i * 256;
        const int row = c >> 3;
        if (row >= 144) break;
        const int ch = (c & 7) * 8;
        int gr = qs + row; if (gr > T - 1) gr = T - 1;
        uint4 uv = *(const uint4*)(qkv + base + (size_t)gr * rs + voff + ch);
        if (row < 128) {
            uint4 uk = *(const uint4*)(qkv + base + (size_t)gr * rs + koff + ch);
            *(uint4*)&k_s[row * 72 + ch] = uk;
        }
        const uint32_t* vp = (const uint32_t*)&uv;
        uint32_t* vd = (uint32_t*)&v_s[row * 66 + ch];
        vd[0] = vp[0]; vd[1] = vp[1]; vd[2] = vp[2]; vd[3] = vp[3];
    }
    __syncthreads();

    bf16x8 aq0, aq1;
    {
        const short* g = qkv + base + (size_t)(qs + 16 * w + l16) * rs + qoff + qd * 8;
        aq0 = *(const bf16x8*)(g);
        aq1 = *(const bf16x8*)(g + 32);
    }

    f32x4 sacc[5] = {};
#pragma unroll
    for (int u = 0; u < 5; ++u) {
        const int krow = 16 * (w + u) + l16;
        bf16x8 bk0 = *(const bf16x8*)&k_s[krow * 72 + qd * 8];
        bf16x8 bk1 = *(const bf16x8*)&k_s[krow * 72 + 32 + qd * 8];
        sacc[u] = __builtin_amdgcn_mfma_f32_16x16x32_bf16(aq0, bk0, sacc[u], 0, 0, 0);
        sacc[u] = __builtin_amdgcn_mfma_f32_16x16x32_bf16(aq1, bk1, sacc[u], 0, 0, 0);
    }

    const float scale = 0.125f;
    float pw[5][4];
    float inv[4];
#pragma unroll
    for (int r = 0; r < 4; ++r) {
        const int m = 4 * qd + r;
        float mx = -3.4e38f;
#pragma unroll
        for (int u = 0; u < 5; ++u) {
            const int rel = 16 * u + l16 - m;
            const int j   = qs + 16 * (w + u) + l16;
            const bool ok = (rel >= 0) & (rel <= 64) & (j < T);
            const float v = ok ? sacc[u][r] * scale : -3.4e38f;
            pw[u][r] = v;
            mx = fmaxf(mx, v);
        }
#pragma unroll
        for (int msk = 1; msk <= 8; msk <<= 1) mx = fmaxf(mx, __shfl_xor(mx, msk));
        float sum = 0.f;
#pragma unroll
        for (int u = 0; u < 5; ++u) {
            float e = (pw[u][r] <= -3.0e38f) ? 0.f : __expf(pw[u][r] - mx);
            pw[u][r] = e;
            sum += e;
        }
#pragma unroll
        for (int msk = 1; msk <= 8; msk <<= 1) sum += __shfl_xor(sum, msk);
        inv[r] = 1.0f / sum;
    }

#pragma unroll
    for (int u = 0; u < 5; ++u)
#pragma unroll
        for (int r = 0; r < 4; ++r)
            p_s[(16 * w + 4 * qd + r) * 104 + 16 * u + l16] = f2bf(pw[u][r] * inv[r]);
#pragma unroll
    for (int r = 0; r < 4; ++r)
        p_s[(16 * w + 4 * qd + r) * 104 + 80 + l16] = 0;
    // wave-private rows; same-wave RAW -> lgkmcnt wait, no barrier needed

    f32x4 oacc[4] = {};
#pragma unroll
    for (int ks = 0; ks < 3; ++ks) {
        bf16x8 ap = *(const bf16x8*)&p_s[(16 * w + l16) * 104 + ks * 32 + qd * 8];
#pragma unroll
        for (int dt = 0; dt < 4; ++dt) {
            short t[8];
#pragma unroll
            for (int j = 0; j < 8; ++j)
                t[j] = v_s[(16 * w + ks * 32 + qd * 8 + j) * 66 + 16 * dt + l16];
            bf16x8 bv = *(const bf16x8*)t;
            oacc[dt] = __builtin_amdgcn_mfma_f32_16x16x32_bf16(bv, ap, oacc[dt], 0, 0, 0);
        }
    }

    const size_t row = (size_t)(b * T + qs + 16 * w + l16);
#pragma unroll
    for (int dt = 0; dt < 4; ++dt) {
        short t[4];
#pragma unroll
        for (int r = 0; r < 4; ++r) t[r] = f2bf(oacc[dt][r]);
        *(uint2*)&attn_out[row * 1024 + h * 64 + dt * 16 + qd * 4] = *(const uint2*)t;
    }
}

extern "C" void kernel_launch(void* const* d_in, const int* in_sizes, int n_in,
                              void* d_out, int out_size, void* d_ws, size_t ws_size,
                              hipStream_t stream) {
    (void)in_sizes; (void)n_in; (void)out_size; (void)ws_size;
    const int B = 2, T = 2048, D = 1024;
    const int M = B * T;  // 4096

    char* ws = (char*)d_ws;
    size_t off = 0;
    short* xb   = (short*)(ws + off); off += (size_t)M * D * 2;       // 8.4 MB
    short* wqkb = (short*)(ws + off); off += (size_t)3 * D * D * 2;   // 6.3 MB
    short* wob  = (short*)(ws + off); off += (size_t)D * D * 2;       // 2.1 MB
    short* qkv  = (short*)(ws + off); off += (size_t)M * 3 * D * 2;   // 25.2 MB
    short* attn = (short*)(ws + off); off += (size_t)M * D * 2;       // 8.4 MB

    convert_all<<<dim3(4096), 256, 0, stream>>>(
        (const float*)d_in[0], (const float*)d_in[1], (const float*)d_in[3],
        xb, wqkb, wob);

    gemm1_qkv_pipe<<<dim3(192), 512, 0, stream>>>(
        xb, wqkb, (const float*)d_in[2], qkv, M, 3 * D, D);
    attn_mfma<<<dim3(T / 64, 16, B), 256, 0, stream>>>(qkv, attn, B, T);
    gemm2_out<<<dim3(D / 128, M / 64), 256, 0, stream>>>(
        attn, wob, (const float*)d_in[4], (float*)d_out, M, D, D);
}